// Round 9
// baseline (201.221 us; speedup 1.0000x reference)
//
#include <hip/hip_runtime.h>
#include <math.h>

typedef __bf16 bf16;
typedef __bf16 bf16x4 __attribute__((ext_vector_type(4)));
typedef __bf16 bf16x8 __attribute__((ext_vector_type(8)));
typedef float f32x4 __attribute__((ext_vector_type(4)));

#define MFMA(a, b, c) __builtin_amdgcn_mfma_f32_16x16x32_bf16(a, b, c, 0, 0, 0)
#define LOG2E 1.44269504088896340736f

// XOR-swizzled 64x64 bf16 tile (8 KB) for GEMM staging (qkv A/W, gemm_out W).
__device__ __forceinline__ void stage_tile256(bf16* __restrict__ T, const bf16* __restrict__ src,
                                              int rs, int t) {
#pragma unroll
    for (int it = 0; it < 2; ++it) {
        int u = it * 256 + t;
        int row = u >> 3, ch = u & 7;
        bf16x8 v = *(const bf16x8*)&src[(size_t)row * rs + ch * 8];
        *(bf16x8*)&T[row * 64 + ((ch ^ (row & 7)) << 3)] = v;
    }
}
__device__ __forceinline__ bf16x8 frag(const bf16* __restrict__ T, int row, int ch) {
    return *(const bf16x8*)&T[row * 64 + ((ch ^ (row & 7)) << 3)];
}

// ---------------- prep: x -> bf16 [0,1024); weights [1024,1536) ----------------
__global__ __launch_bounds__(256) void prep(
    const float* __restrict__ x,
    const float* __restrict__ Wq, const float* __restrict__ Wk,
    const float* __restrict__ Wv, const float* __restrict__ Wo,
    bf16* __restrict__ xb, bf16* __restrict__ Wb,
    bf16* __restrict__ Woh, bf16* __restrict__ Wol)
{
    int bid = blockIdx.x, t = threadIdx.x;
    if (bid < 1024) {
        int i = (bid * 256 + t) * 8;
        float4 a = *(const float4*)&x[i];
        float4 c = *(const float4*)&x[i + 4];
        float v[8] = {a.x, a.y, a.z, a.w, c.x, c.y, c.z, c.w};
        bf16x8 o;
#pragma unroll
        for (int u = 0; u < 8; ++u) o[u] = (bf16)v[u];
        *(bf16x8*)&xb[i] = o;
    } else {
        int zb = bid - 1024;
        int z = zb >> 7;
        int i = ((zb & 127) * 256 + t) * 8;
        const float* src = (z == 0) ? Wq : (z == 1) ? Wk : (z == 2) ? Wv : Wo;
        float4 a = *(const float4*)&src[i];
        float4 c = *(const float4*)&src[i + 4];
        float v[8] = {a.x, a.y, a.z, a.w, c.x, c.y, c.z, c.w};
        if (z < 3) {
            bf16x8 o;
#pragma unroll
            for (int u = 0; u < 8; ++u) o[u] = (bf16)v[u];
            *(bf16x8*)&Wb[(size_t)z * 262144 + i] = o;
        } else {
            bf16x8 oh, ol;
#pragma unroll
            for (int u = 0; u < 8; ++u) {
                bf16 hi = (bf16)v[u];
                oh[u] = hi;
                ol[u] = (bf16)(v[u] - (float)hi);
            }
            *(bf16x8*)&Woh[i] = oh;
            *(bf16x8*)&Wol[i] = ol;
        }
    }
}

// ---------------- qkv GEMM (bid<768) + mask bit-pack (bid in [768,2816)) ----------------
// GEMM: 64x128 tiles; z=0 -> Q natural layout [bh][tok][64] (scaled 0.125*log2e);
// z=1 -> K in A-frag order Kf[bh][jt][nc*2+c][lane][8]; z=2 -> V in B-frag order
// Vf[bh][jt][dc*2+c][lane][8] (element d=dc*16+(lane&15), j=j0+c*32+(lane>>4)*8+i).
__global__ __launch_bounds__(256) void qkv_mask(
    const bf16* __restrict__ A, const bf16* __restrict__ Wb,
    const int* __restrict__ seqm, const int* __restrict__ spm,
    bf16* __restrict__ Qg, bf16* __restrict__ Kf, bf16* __restrict__ Vf,
    unsigned* __restrict__ pseq, unsigned* __restrict__ psp)
{
    int bid = blockIdx.x, t = threadIdx.x;
    if (bid >= 768) {
        // ---- mask pack: 1 row per wave, ballot-coalesced ----
        int wave = t >> 6, lane = t & 63;
        int row = (bid - 768) * 4 + wave;       // [0,4096)=seq, [4096,8192)=sparse
        const int* src = (row < 4096) ? (seqm + (size_t)row * 2048)
                                      : (spm + (size_t)(row - 4096) * 2048);
        unsigned* dst = (row < 4096) ? (pseq + (size_t)row * 64)
                                     : (psp + (size_t)(row - 4096) * 64);
        unsigned myw = 0;
#pragma unroll
        for (int u = 0; u < 32; ++u) {
            int v = src[u * 64 + lane];
            unsigned long long bal = __ballot(v != 0);
            if ((lane >> 1) == u)
                myw = (lane & 1) ? (unsigned)(bal >> 32) : (unsigned)bal;
        }
        dst[lane] = myw;
        return;
    }

    __shared__ bf16 AT[4096], WT0[4096], WT1[4096];
    __shared__ bf16 Lt[64 * 72];
    int m0b = bid & 63;
    int rest = bid >> 6;
    int np = rest & 3, z = rest >> 2;
    const bf16* W = Wb + (size_t)z * 262144;

    int wave = t >> 6, lane = t & 63, l = lane & 15, quad = lane >> 4;
    int m0 = m0b * 64 + wave * 16;
    int nb = np * 128;
    f32x4 acc[8] = {};
    for (int k0 = 0; k0 < 512; k0 += 64) {
        __syncthreads();
        stage_tile256(AT, A + (size_t)m0b * 64 * 512 + k0, 512, t);
        stage_tile256(WT0, W + (size_t)nb * 512 + k0, 512, t);
        stage_tile256(WT1, W + (size_t)(nb + 64) * 512 + k0, 512, t);
        __syncthreads();
        bf16x8 a0 = frag(AT, wave * 16 + l, quad);
        bf16x8 a1 = frag(AT, wave * 16 + l, 4 + quad);
#pragma unroll
        for (int nc = 0; nc < 4; ++nc) {
            bf16x8 b0 = frag(WT0, nc * 16 + l, quad);
            bf16x8 b1 = frag(WT0, nc * 16 + l, 4 + quad);
            acc[nc] = MFMA(a0, b0, acc[nc]);
            acc[nc] = MFMA(a1, b1, acc[nc]);
        }
#pragma unroll
        for (int nc = 0; nc < 4; ++nc) {
            bf16x8 b0 = frag(WT1, nc * 16 + l, quad);
            bf16x8 b1 = frag(WT1, nc * 16 + l, 4 + quad);
            acc[4 + nc] = MFMA(a0, b0, acc[4 + nc]);
            acc[4 + nc] = MFMA(a1, b1, acc[4 + nc]);
        }
    }

    int b = m0b >> 5, jt = m0b & 31;
    if (z == 0) {
        float scale = 0.125f * LOG2E;
#pragma unroll
        for (int nc = 0; nc < 8; ++nc) {
#pragma unroll
            for (int r = 0; r < 4; ++r) {
                int m = m0 + quad * 4 + r;
                int feat = nb + nc * 16 + l;
                int bb = m >> 11, tok = m & 2047, h = feat >> 6, d = feat & 63;
                Qg[(((size_t)(bb * 8 + h)) * 2048 + tok) * 64 + d] = (bf16)(acc[nc][r] * scale);
            }
        }
    } else {
        bf16* dstbuf = (z == 1) ? Kf : Vf;
#pragma unroll
        for (int hh = 0; hh < 2; ++hh) {
            int h = np * 2 + hh, bhh = b * 8 + h;
            __syncthreads();
            if (z == 1) {
                // Lt[j_local][d_head]
#pragma unroll
                for (int nc4 = 0; nc4 < 4; ++nc4)
#pragma unroll
                    for (int r = 0; r < 4; ++r)
                        Lt[(wave * 16 + quad * 4 + r) * 72 + nc4 * 16 + l] = (bf16)acc[hh * 4 + nc4][r];
            } else {
                // Lt[d_head][j_local]
#pragma unroll
                for (int nc4 = 0; nc4 < 4; ++nc4)
#pragma unroll
                    for (int r = 0; r < 4; ++r)
                        Lt[(nc4 * 16 + l) * 72 + wave * 16 + quad * 4 + r] = (bf16)acc[hh * 4 + nc4][r];
            }
            __syncthreads();
            // groups g = pair*2+c (8), lane2 (64): read Lt[(g>>1)*16 + (lane2&15)][ (g&1)*32 + (lane2>>4)*8 .. +7 ]
            size_t base = ((size_t)(bhh * 32 + jt)) * 4096;
#pragma unroll
            for (int p = 0; p < 2; ++p) {
                int gi = p * 256 + t;
                int g = gi >> 6, lane2 = gi & 63;
                int l15 = lane2 & 15, q = lane2 >> 4;
                bf16x8 v = *(const bf16x8*)&Lt[((g >> 1) * 16 + l15) * 72 + (g & 1) * 32 + q * 8];
                *(bf16x8*)&dstbuf[base + (size_t)g * 512 + lane2 * 8] = v;
            }
        }
    }
}

// ---------------- flash attention: frag-layout K/V direct from global, NO barriers ----------------
// grid 2048 = jc(2b) | it(5b) | bh(4b); 4 waves; LDS = 9 KB (per-wave P only).
// p = bit ? exp2(s) : 0 (Q pre-scaled by 0.125*log2e).
__global__ __launch_bounds__(256) void attn_kernel(
    const bf16* __restrict__ Qg, const bf16* __restrict__ Kf, const bf16* __restrict__ Vf,
    const unsigned* __restrict__ pseq, const unsigned* __restrict__ psp,
    float* __restrict__ Opart, float* __restrict__ Lpart)
{
    __shared__ bf16 P[4 * 16 * 72];
    int bid = blockIdx.x;
    int bh = bid & 15;                       // XCD = bid%8 -> K/V L2-resident (1 MB/XCD)
    int it = (bid >> 4) & 31;
    int jc = bid >> 9;
    int i0 = it * 64;
    int b = bh >> 3, par = bh & 1;
    int t = threadIdx.x, rg = t >> 6, lane = t & 63, l = lane & 15, quad = lane >> 4;

    const bf16* Qp = Qg + ((size_t)bh * 2048 + i0 + rg * 16 + l) * 64;
    bf16x8 qf0 = *(const bf16x8*)&Qp[quad * 8];
    bf16x8 qf1 = *(const bf16x8*)&Qp[32 + quad * 8];

    bf16x8 ones;
#pragma unroll
    for (int i = 0; i < 8; ++i) ones[i] = (bf16)1.0f;
    const f32x4 fz = {0.f, 0.f, 0.f, 0.f};

    f32x4 o_acc[4] = {}, l_acc = {};

    int qrow = i0 + rg * 16 + l;
    const unsigned* seqp = pseq + (size_t)b * 131072 + (size_t)qrow * 64;
    const unsigned* sppp = psp + (size_t)par * 131072 + (size_t)qrow * 64;
    const bf16* Kb = Kf + (size_t)bh * 32 * 4096 + lane * 8;
    const bf16* Vb = Vf + (size_t)bh * 32 * 4096 + lane * 8;
    bf16* Pw = P + rg * 1152 + l * 72;
    const bf16* Pr = P + rg * 1152;

    int jlo = jc * 512, jhi = jlo + 512;
    for (int j0 = jlo; j0 < jhi; j0 += 64) {
        int jt = j0 >> 6;
        uint2 mseq = *(const uint2*)&seqp[j0 >> 5];
        uint2 msp = *(const uint2*)&sppp[j0 >> 5];
        unsigned w0 = mseq.x & msp.x, w1 = mseq.y & msp.y;

        // K fragments: contiguous 1 KB per wave-instr (frag-order layout)
        const bf16* Kt = Kb + (size_t)jt * 4096;
        bf16x8 kf[4][2];
#pragma unroll
        for (int nc = 0; nc < 4; ++nc) {
            kf[nc][0] = *(const bf16x8*)&Kt[(nc * 2 + 0) * 512];
            kf[nc][1] = *(const bf16x8*)&Kt[(nc * 2 + 1) * 512];
        }

        // S^T = K·Q^T (col = query lane)
        f32x4 s[4];
#pragma unroll
        for (int nc = 0; nc < 4; ++nc) {
            s[nc] = MFMA(kf[nc][0], qf0, fz);
            s[nc] = MFMA(kf[nc][1], qf1, s[nc]);
        }

        // V fragments issued here: latency hides under softmax VALU work
        const bf16* Vt2 = Vb + (size_t)jt * 4096;
        bf16x8 vf[4][2];
#pragma unroll
        for (int dc = 0; dc < 4; ++dc) {
            vf[dc][0] = *(const bf16x8*)&Vt2[(dc * 2 + 0) * 512];
            vf[dc][1] = *(const bf16x8*)&Vt2[(dc * 2 + 1) * 512];
        }

        // fixed-max softmax: p = bit ? exp2(s) : 0
#pragma unroll
        for (int nc = 0; nc < 4; ++nc) {
            unsigned w = (nc < 2) ? w0 : w1;
            int bbase = (nc & 1) * 16 + quad * 4;
            bf16x4 pv;
#pragma unroll
            for (int r = 0; r < 4; ++r) {
                float e = __builtin_amdgcn_exp2f(s[nc][r]);
                pv[r] = (bf16)(((w >> (bbase + r)) & 1u) ? e : 0.f);
            }
            *(bf16x4*)&Pw[nc * 16 + quad * 4] = pv;
        }

        // P A-frags (same-wave LDS round trip; lgkmcnt ordering only)
        bf16x8 pa0 = *(const bf16x8*)&Pr[l * 72 + quad * 8];
        bf16x8 pa1 = *(const bf16x8*)&Pr[l * 72 + 32 + quad * 8];
        l_acc = MFMA(pa0, ones, l_acc);
        l_acc = MFMA(pa1, ones, l_acc);
#pragma unroll
        for (int dc = 0; dc < 4; ++dc) {
            o_acc[dc] = MFMA(pa0, vf[dc][0], o_acc[dc]);
            o_acc[dc] = MFMA(pa1, vf[dc][1], o_acc[dc]);
        }
    }

    size_t pb = ((size_t)((bh * 32 + it) * 4 + jc)) * 4096;
#pragma unroll
    for (int dc = 0; dc < 4; ++dc)
#pragma unroll
        for (int r = 0; r < 4; ++r)
            Opart[pb + (size_t)(rg * 16 + quad * 4 + r) * 64 + dc * 16 + l] = o_acc[dc][r];
    if (l == 0) {
#pragma unroll
        for (int r = 0; r < 4; ++r)
            Lpart[((bh * 32 + it) * 4 + jc) * 64 + rg * 16 + quad * 4 + r] = l_acc[r];
    }
}

// ---------------- output projection with fused combine + normalize + hi/lo split ----------------
__global__ __launch_bounds__(256) void gemm_out(
    const float* __restrict__ Opart, const float* __restrict__ Lpart,
    const bf16* __restrict__ Wh, const bf16* __restrict__ Wl,
    float* __restrict__ C)
{
    __shared__ bf16 AhT[4096], AlT[4096], WhT[4096], WlT[4096];
    __shared__ float Linv[512];
    int bid = blockIdx.x;
    int m0b = bid & 63, n0 = bid >> 6;
    int t = threadIdx.x, wave = t >> 6, lane = t & 63, l = lane & 15, quad = lane >> 4;
    int m0 = m0b * 64 + wave * 16;
    int nb = n0 * 64;
    int b = m0b >> 5, itA = m0b & 31;

    // per-block inverse row-sum table [h][row]
    {
        int h = t >> 6, row = t & 63;
        float s0 = 0.f, s1 = 0.f;
#pragma unroll
        for (int jc = 0; jc < 4; ++jc) {
            s0 += Lpart[((((b * 8 + h) * 32 + itA) * 4) + jc) * 64 + row];
            s1 += Lpart[((((b * 8 + 4 + h) * 32 + itA) * 4) + jc) * 64 + row];
        }
        Linv[t] = 1.0f / s0;
        Linv[256 + t] = 1.0f / s1;
    }

    f32x4 acc[4] = {};
    for (int k0 = 0; k0 < 512; k0 += 64) {
        int h = k0 >> 6;
        size_t slab = ((size_t)((b * 8 + h) * 32 + itA)) * 4;
        __syncthreads();
        // stage A: sum 4 jc partials, normalize, hi/lo split, swizzled store
#pragma unroll
        for (int itr = 0; itr < 2; ++itr) {
            int u = itr * 256 + t;
            int row = u >> 3, ch = u & 7;
            float vv[8] = {};
#pragma unroll
            for (int jc = 0; jc < 4; ++jc) {
                const float* Op = Opart + (slab + jc) * 4096 + (size_t)row * 64 + ch * 8;
                float4 v0 = *(const float4*)&Op[0];
                float4 v1 = *(const float4*)&Op[4];
                vv[0] += v0.x; vv[1] += v0.y; vv[2] += v0.z; vv[3] += v0.w;
                vv[4] += v1.x; vv[5] += v1.y; vv[6] += v1.z; vv[7] += v1.w;
            }
            float inv = Linv[h * 64 + row];
            bf16x8 hi, lo;
#pragma unroll
            for (int i = 0; i < 8; ++i) {
                float o = vv[i] * inv;
                bf16 hb = (bf16)o;
                hi[i] = hb;
                lo[i] = (bf16)(o - (float)hb);
            }
            int dst = row * 64 + ((ch ^ (row & 7)) << 3);
            *(bf16x8*)&AhT[dst] = hi;
            *(bf16x8*)&AlT[dst] = lo;
        }
        stage_tile256(WhT, Wh + (size_t)nb * 512 + k0, 512, t);
        stage_tile256(WlT, Wl + (size_t)nb * 512 + k0, 512, t);
        __syncthreads();
        bf16x8 ah0 = frag(AhT, wave * 16 + l, quad);
        bf16x8 ah1 = frag(AhT, wave * 16 + l, 4 + quad);
        bf16x8 al0 = frag(AlT, wave * 16 + l, quad);
        bf16x8 al1 = frag(AlT, wave * 16 + l, 4 + quad);
#pragma unroll
        for (int nc = 0; nc < 4; ++nc) {
            bf16x8 bh0 = frag(WhT, nc * 16 + l, quad);
            bf16x8 bh1 = frag(WhT, nc * 16 + l, 4 + quad);
            bf16x8 bl0 = frag(WlT, nc * 16 + l, quad);
            bf16x8 bl1 = frag(WlT, nc * 16 + l, 4 + quad);
            acc[nc] = MFMA(ah0, bh0, acc[nc]);
            acc[nc] = MFMA(ah1, bh1, acc[nc]);
            acc[nc] = MFMA(ah0, bl0, acc[nc]);
            acc[nc] = MFMA(ah1, bl1, acc[nc]);
            acc[nc] = MFMA(al0, bh0, acc[nc]);
            acc[nc] = MFMA(al1, bh1, acc[nc]);
        }
    }
#pragma unroll
    for (int nc = 0; nc < 4; ++nc)
#pragma unroll
        for (int r = 0; r < 4; ++r)
            C[(size_t)(m0 + quad * 4 + r) * 512 + nb + nc * 16 + l] = acc[nc][r];
}

extern "C" void kernel_launch(void* const* d_in, const int* in_sizes, int n_in,
                              void* d_out, int out_size, void* d_ws, size_t ws_size,
                              hipStream_t stream) {
    const float* x = (const float*)d_in[0];
    const float* Wq = (const float*)d_in[1];
    const float* Wk = (const float*)d_in[2];
    const float* Wv = (const float*)d_in[3];
    const float* Wo = (const float*)d_in[4];
    const int* seqm = (const int*)d_in[5];
    const int* spm = (const int*)d_in[6];
    float* out = (float*)d_out;

    const size_t E = 2097152;            // 2*2048*512
    bf16* xb = (bf16*)d_ws;
    bf16* Wb = xb + E;
    bf16* Woh = Wb + 786432;
    bf16* Wol = Woh + 262144;
    bf16* Qg = Wol + 262144;             // [bh][tok][64]
    bf16* Kf = Qg + E;                   // frag order [bh][jt][8][64][8]
    bf16* Vf = Kf + E;                   // frag order
    unsigned* pseq = (unsigned*)(Vf + E);
    unsigned* psp = pseq + 262144;
    float* Opart = (float*)(psp + 262144);       // 2048 slabs x 4096 fp32 = 32 MB
    float* Lpart = Opart + (size_t)2048 * 4096;  // 0.5 MB

    hipLaunchKernelGGL(prep, dim3(1536), dim3(256), 0, stream,
                       x, Wq, Wk, Wv, Wo, xb, Wb, Woh, Wol);
    hipLaunchKernelGGL(qkv_mask, dim3(2816), dim3(256), 0, stream,
                       xb, Wb, seqm, spm, Qg, Kf, Vf, pseq, psp);
    hipLaunchKernelGGL(attn_kernel, dim3(2048), dim3(256), 0, stream,
                       Qg, Kf, Vf, pseq, psp, Opart, Lpart);
    hipLaunchKernelGGL(gemm_out, dim3(512), dim3(256), 0, stream, Opart, Lpart, Woh, Wol, out);
}

// Round 10
// 200.278 us; speedup vs baseline: 1.0047x; 1.0047x over previous
//
#include <hip/hip_runtime.h>
#include <math.h>

typedef __bf16 bf16;
typedef __bf16 bf16x4 __attribute__((ext_vector_type(4)));
typedef __bf16 bf16x8 __attribute__((ext_vector_type(8)));
typedef float f32x4 __attribute__((ext_vector_type(4)));

#define MFMA(a, b, c) __builtin_amdgcn_mfma_f32_16x16x32_bf16(a, b, c, 0, 0, 0)
#define LOG2E 1.44269504088896340736f

// XOR-swizzled 64x64 bf16 tile (8 KB): elem (row, chunk8) at row*64 + ((ch^(row&7))*8).
__device__ __forceinline__ void stage_tile256(bf16* __restrict__ T, const bf16* __restrict__ src,
                                              int rs, int t) {
#pragma unroll
    for (int it = 0; it < 2; ++it) {
        int u = it * 256 + t;
        int row = u >> 3, ch = u & 7;
        bf16x8 v = *(const bf16x8*)&src[(size_t)row * rs + ch * 8];
        *(bf16x8*)&T[row * 64 + ((ch ^ (row & 7)) << 3)] = v;
    }
}
// Same, but source is fp32 (convert to bf16 during staging).
__device__ __forceinline__ void stage_tile256_cvt(bf16* __restrict__ T, const float* __restrict__ src,
                                                  int rs, int t) {
#pragma unroll
    for (int it = 0; it < 2; ++it) {
        int u = it * 256 + t;
        int row = u >> 3, ch = u & 7;
        const float* p = &src[(size_t)row * rs + ch * 8];
        float4 a = *(const float4*)&p[0];
        float4 c = *(const float4*)&p[4];
        float vv[8] = {a.x, a.y, a.z, a.w, c.x, c.y, c.z, c.w};
        bf16x8 o;
#pragma unroll
        for (int i = 0; i < 8; ++i) o[i] = (bf16)vv[i];
        *(bf16x8*)&T[row * 64 + ((ch ^ (row & 7)) << 3)] = o;
    }
}
__device__ __forceinline__ bf16x8 frag(const bf16* __restrict__ T, int row, int ch) {
    return *(const bf16x8*)&T[row * 64 + ((ch ^ (row & 7)) << 3)];
}

// ---------------- qkv GEMM (bid<768, fp32 sources) + mask bit-pack [768,2816) ----------------
// z=0 -> Q [bh][tok][64] scaled 0.125*log2e; z=1 -> K [bh][tok][64]; z=2 -> V transposed [bh][64][2048].
__global__ __launch_bounds__(256) void qkv_mask(
    const float* __restrict__ x,
    const float* __restrict__ Wq, const float* __restrict__ Wk, const float* __restrict__ Wv,
    const int* __restrict__ seqm, const int* __restrict__ spm,
    bf16* __restrict__ Qg, bf16* __restrict__ Kg, bf16* __restrict__ Vt,
    unsigned* __restrict__ pseq, unsigned* __restrict__ psp)
{
    int bid = blockIdx.x, t = threadIdx.x;
    if (bid >= 768) {
        int wave = t >> 6, lane = t & 63;
        int row = (bid - 768) * 4 + wave;       // [0,4096)=seq, [4096,8192)=sparse
        const int* src = (row < 4096) ? (seqm + (size_t)row * 2048)
                                      : (spm + (size_t)(row - 4096) * 2048);
        unsigned* dst = (row < 4096) ? (pseq + (size_t)row * 64)
                                     : (psp + (size_t)(row - 4096) * 64);
        unsigned myw = 0;
#pragma unroll
        for (int u = 0; u < 32; ++u) {
            int v = src[u * 64 + lane];
            unsigned long long bal = __ballot(v != 0);
            if ((lane >> 1) == u)
                myw = (lane & 1) ? (unsigned)(bal >> 32) : (unsigned)bal;
        }
        dst[lane] = myw;
        return;
    }

    __shared__ bf16 AT[4096], WT0[4096], WT1[4096];
    __shared__ bf16 Lt[64 * 72];
    int m0b = bid & 63;
    int rest = bid >> 6;
    int np = rest & 3, z = rest >> 2;
    const float* W = (z == 0) ? Wq : (z == 1) ? Wk : Wv;

    int wave = t >> 6, lane = t & 63, l = lane & 15, quad = lane >> 4;
    int m0 = m0b * 64 + wave * 16;
    int nb = np * 128;
    f32x4 acc[8] = {};
    for (int k0 = 0; k0 < 512; k0 += 64) {
        __syncthreads();
        stage_tile256_cvt(AT, x + (size_t)m0b * 64 * 512 + k0, 512, t);
        stage_tile256_cvt(WT0, W + (size_t)nb * 512 + k0, 512, t);
        stage_tile256_cvt(WT1, W + (size_t)(nb + 64) * 512 + k0, 512, t);
        __syncthreads();
        bf16x8 a0 = frag(AT, wave * 16 + l, quad);
        bf16x8 a1 = frag(AT, wave * 16 + l, 4 + quad);
#pragma unroll
        for (int nc = 0; nc < 4; ++nc) {
            bf16x8 b0 = frag(WT0, nc * 16 + l, quad);
            bf16x8 b1 = frag(WT0, nc * 16 + l, 4 + quad);
            acc[nc] = MFMA(a0, b0, acc[nc]);
            acc[nc] = MFMA(a1, b1, acc[nc]);
        }
#pragma unroll
        for (int nc = 0; nc < 4; ++nc) {
            bf16x8 b0 = frag(WT1, nc * 16 + l, quad);
            bf16x8 b1 = frag(WT1, nc * 16 + l, 4 + quad);
            acc[4 + nc] = MFMA(a0, b0, acc[4 + nc]);
            acc[4 + nc] = MFMA(a1, b1, acc[4 + nc]);
        }
    }
    if (z < 2) {
        bf16* out = (z == 0) ? Qg : Kg;
        float scale = (z == 0) ? (0.125f * LOG2E) : 1.0f;
#pragma unroll
        for (int nc = 0; nc < 8; ++nc) {
#pragma unroll
            for (int r = 0; r < 4; ++r) {
                int m = m0 + quad * 4 + r;
                int feat = nb + nc * 16 + l;
                int bb = m >> 11, tok = m & 2047, h = feat >> 6, d = feat & 63;
                out[(((size_t)(bb * 8 + h)) * 2048 + tok) * 64 + d] = (bf16)(acc[nc][r] * scale);
            }
        }
    } else {
        int b = m0b >> 5;
#pragma unroll
        for (int hh = 0; hh < 2; ++hh) {
            __syncthreads();
#pragma unroll
            for (int nc = 0; nc < 4; ++nc)
#pragma unroll
                for (int r = 0; r < 4; ++r)
                    Lt[(nc * 16 + l) * 72 + wave * 16 + quad * 4 + r] = (bf16)acc[hh * 4 + nc][r];
            __syncthreads();
            int d = t >> 2, seg = t & 3;
            int tok0 = m0b * 64;
            int h = np * 2 + hh;
            bf16x8 o0, o1;
#pragma unroll
            for (int i = 0; i < 8; ++i) { o0[i] = Lt[d * 72 + seg * 16 + i]; o1[i] = Lt[d * 72 + seg * 16 + 8 + i]; }
            size_t base = ((size_t)(b * 8 + h) * 64 + d) * 2048 + (tok0 & 2047) + seg * 16;
            *(bf16x8*)&Vt[base] = o0;
            *(bf16x8*)&Vt[base + 8] = o1;
        }
    }
}

// ---------------- flash attention: 128 q-rows/block, K/V staged once, 2 passes ----------------
// grid 1024 = jc(2b) | it(4b) | bh(4b); 4 waves; LDS ~35 KB -> 4 blocks/CU.
__global__ __launch_bounds__(256) void attn_kernel(
    const bf16* __restrict__ Qg, const bf16* __restrict__ Kg, const bf16* __restrict__ Vt,
    const unsigned* __restrict__ pseq, const unsigned* __restrict__ psp,
    float* __restrict__ Opart, float* __restrict__ Lpart)
{
    __shared__ bf16 KT[4096], VT[4096];
    __shared__ bf16 P[8 * 1152];             // [wave*2+pass][16][72]
    int bid = blockIdx.x;
    int bh = bid & 15;                       // XCD = bid%8 -> K/V L2-resident
    int it = (bid >> 4) & 15;
    int jc = bid >> 8;
    int i0 = it * 128;
    int b = bh >> 3, par = bh & 1;
    int t = threadIdx.x, rg = t >> 6, lane = t & 63, l = lane & 15, quad = lane >> 4;

    bf16x8 qf[2][2];
    const unsigned* seqp[2];
    const unsigned* sppp[2];
#pragma unroll
    for (int p = 0; p < 2; ++p) {
        int qrow = i0 + p * 64 + rg * 16 + l;
        const bf16* Qp = Qg + ((size_t)bh * 2048 + qrow) * 64;
        qf[p][0] = *(const bf16x8*)&Qp[quad * 8];
        qf[p][1] = *(const bf16x8*)&Qp[32 + quad * 8];
        seqp[p] = pseq + (size_t)b * 131072 + (size_t)qrow * 64;
        sppp[p] = psp + (size_t)par * 131072 + (size_t)qrow * 64;
    }

    bf16x8 ones;
#pragma unroll
    for (int i = 0; i < 8; ++i) ones[i] = (bf16)1.0f;
    const f32x4 fz = {0.f, 0.f, 0.f, 0.f};

    f32x4 o_acc[2][4] = {};
    f32x4 l_acc[2] = {};

    const bf16* Kbase = Kg + (size_t)bh * 2048 * 64;
    const bf16* Vbase = Vt + (size_t)bh * 64 * 2048;

    int jlo = jc * 512, jhi = jlo + 512;
    for (int j0 = jlo; j0 < jhi; j0 += 64) {
        uint2 mq[2], ms[2];
#pragma unroll
        for (int p = 0; p < 2; ++p) {
            mq[p] = *(const uint2*)&seqp[p][j0 >> 5];
            ms[p] = *(const uint2*)&sppp[p][j0 >> 5];
        }
        __syncthreads();
        stage_tile256(KT, Kbase + (size_t)j0 * 64, 64, t);
        stage_tile256(VT, Vbase + j0, 2048, t);
        __syncthreads();

#pragma unroll
        for (int p = 0; p < 2; ++p) {
            bf16* Pw = P + (rg * 2 + p) * 1152 + l * 72;
            const bf16* Pr = P + (rg * 2 + p) * 1152;
            unsigned w0 = mq[p].x & ms[p].x, w1 = mq[p].y & ms[p].y;

            // S^T = K·Q^T (col = query lane)
            f32x4 s[4];
#pragma unroll
            for (int nc = 0; nc < 4; ++nc) {
                s[nc] = MFMA(frag(KT, nc * 16 + l, quad), qf[p][0], fz);
                s[nc] = MFMA(frag(KT, nc * 16 + l, 4 + quad), qf[p][1], s[nc]);
            }

            // fixed-max softmax: p = bit ? exp2(s) : 0
#pragma unroll
            for (int nc = 0; nc < 4; ++nc) {
                unsigned w = (nc < 2) ? w0 : w1;
                int bbase = (nc & 1) * 16 + quad * 4;
                bf16x4 pv;
#pragma unroll
                for (int r = 0; r < 4; ++r) {
                    float e = __builtin_amdgcn_exp2f(s[nc][r]);
                    pv[r] = (bf16)(((w >> (bbase + r)) & 1u) ? e : 0.f);
                }
                *(bf16x4*)&Pw[nc * 16 + quad * 4] = pv;
            }

            bf16x8 pa0 = *(const bf16x8*)&Pr[l * 72 + quad * 8];
            bf16x8 pa1 = *(const bf16x8*)&Pr[l * 72 + 32 + quad * 8];
            l_acc[p] = MFMA(pa0, ones, l_acc[p]);
            l_acc[p] = MFMA(pa1, ones, l_acc[p]);
#pragma unroll
            for (int dc = 0; dc < 4; ++dc) {
                o_acc[p][dc] = MFMA(pa0, frag(VT, dc * 16 + l, quad), o_acc[p][dc]);
                o_acc[p][dc] = MFMA(pa1, frag(VT, dc * 16 + l, 4 + quad), o_acc[p][dc]);
            }
        }
    }

#pragma unroll
    for (int p = 0; p < 2; ++p) {
        size_t pb = ((size_t)((bh * 32 + it * 2 + p) * 4 + jc)) * 4096;
#pragma unroll
        for (int dc = 0; dc < 4; ++dc)
#pragma unroll
            for (int r = 0; r < 4; ++r)
                Opart[pb + (size_t)(rg * 16 + quad * 4 + r) * 64 + dc * 16 + l] = o_acc[p][dc][r];
        if (l == 0) {
#pragma unroll
            for (int r = 0; r < 4; ++r)
                Lpart[((bh * 32 + it * 2 + p) * 4 + jc) * 64 + rg * 16 + quad * 4 + r] = l_acc[p][r];
        }
    }
}

// ---------------- output projection: combine + normalize + split, Wo staged from fp32 ----------------
__global__ __launch_bounds__(256) void gemm_out(
    const float* __restrict__ Opart, const float* __restrict__ Lpart,
    const float* __restrict__ Wo, float* __restrict__ C)
{
    __shared__ bf16 AhT[4096], AlT[4096], WhT[4096], WlT[4096];
    __shared__ float Linv[512];
    int bid = blockIdx.x;
    int m0b = bid & 63, n0 = bid >> 6;
    int t = threadIdx.x, wave = t >> 6, lane = t & 63, l = lane & 15, quad = lane >> 4;
    int m0 = m0b * 64 + wave * 16;
    int nb = n0 * 64;
    int b = m0b >> 5, itA = m0b & 31;

    {
        int h = t >> 6, row = t & 63;
        float s0 = 0.f, s1 = 0.f;
#pragma unroll
        for (int jc = 0; jc < 4; ++jc) {
            s0 += Lpart[((((b * 8 + h) * 32 + itA) * 4) + jc) * 64 + row];
            s1 += Lpart[((((b * 8 + 4 + h) * 32 + itA) * 4) + jc) * 64 + row];
        }
        Linv[t] = 1.0f / s0;
        Linv[256 + t] = 1.0f / s1;
    }

    f32x4 acc[4] = {};
    for (int k0 = 0; k0 < 512; k0 += 64) {
        int h = k0 >> 6;
        size_t slab = ((size_t)((b * 8 + h) * 32 + itA)) * 4;
        __syncthreads();
        // A: sum 4 jc partials, normalize, hi/lo split, swizzled store
#pragma unroll
        for (int itr = 0; itr < 2; ++itr) {
            int u = itr * 256 + t;
            int row = u >> 3, ch = u & 7;
            float vv[8] = {};
#pragma unroll
            for (int jc = 0; jc < 4; ++jc) {
                const float* Op = Opart + (slab + jc) * 4096 + (size_t)row * 64 + ch * 8;
                float4 v0 = *(const float4*)&Op[0];
                float4 v1 = *(const float4*)&Op[4];
                vv[0] += v0.x; vv[1] += v0.y; vv[2] += v0.z; vv[3] += v0.w;
                vv[4] += v1.x; vv[5] += v1.y; vv[6] += v1.z; vv[7] += v1.w;
            }
            float inv = Linv[h * 64 + row];
            bf16x8 hi, lo;
#pragma unroll
            for (int i = 0; i < 8; ++i) {
                float o = vv[i] * inv;
                bf16 hb = (bf16)o;
                hi[i] = hb;
                lo[i] = (bf16)(o - (float)hb);
            }
            int dst = row * 64 + ((ch ^ (row & 7)) << 3);
            *(bf16x8*)&AhT[dst] = hi;
            *(bf16x8*)&AlT[dst] = lo;
        }
        // W: fp32 -> hi/lo split during staging
#pragma unroll
        for (int itr = 0; itr < 2; ++itr) {
            int u = itr * 256 + t;
            int row = u >> 3, ch = u & 7;
            const float* Wp = Wo + (size_t)(nb + row) * 512 + k0 + ch * 8;
            float4 v0 = *(const float4*)&Wp[0];
            float4 v1 = *(const float4*)&Wp[4];
            float vv[8] = {v0.x, v0.y, v0.z, v0.w, v1.x, v1.y, v1.z, v1.w};
            bf16x8 hi, lo;
#pragma unroll
            for (int i = 0; i < 8; ++i) {
                bf16 hb = (bf16)vv[i];
                hi[i] = hb;
                lo[i] = (bf16)(vv[i] - (float)hb);
            }
            int dst = row * 64 + ((ch ^ (row & 7)) << 3);
            *(bf16x8*)&WhT[dst] = hi;
            *(bf16x8*)&WlT[dst] = lo;
        }
        __syncthreads();
        bf16x8 ah0 = frag(AhT, wave * 16 + l, quad);
        bf16x8 ah1 = frag(AhT, wave * 16 + l, 4 + quad);
        bf16x8 al0 = frag(AlT, wave * 16 + l, quad);
        bf16x8 al1 = frag(AlT, wave * 16 + l, 4 + quad);
#pragma unroll
        for (int nc = 0; nc < 4; ++nc) {
            bf16x8 bh0 = frag(WhT, nc * 16 + l, quad);
            bf16x8 bh1 = frag(WhT, nc * 16 + l, 4 + quad);
            bf16x8 bl0 = frag(WlT, nc * 16 + l, quad);
            bf16x8 bl1 = frag(WlT, nc * 16 + l, 4 + quad);
            acc[nc] = MFMA(ah0, bh0, acc[nc]);
            acc[nc] = MFMA(ah1, bh1, acc[nc]);
            acc[nc] = MFMA(ah0, bl0, acc[nc]);
            acc[nc] = MFMA(ah1, bl1, acc[nc]);
            acc[nc] = MFMA(al0, bh0, acc[nc]);
            acc[nc] = MFMA(al1, bh1, acc[nc]);
        }
    }
#pragma unroll
    for (int nc = 0; nc < 4; ++nc)
#pragma unroll
        for (int r = 0; r < 4; ++r)
            C[(size_t)(m0 + quad * 4 + r) * 512 + nb + nc * 16 + l] = acc[nc][r];
}

extern "C" void kernel_launch(void* const* d_in, const int* in_sizes, int n_in,
                              void* d_out, int out_size, void* d_ws, size_t ws_size,
                              hipStream_t stream) {
    const float* x = (const float*)d_in[0];
    const float* Wq = (const float*)d_in[1];
    const float* Wk = (const float*)d_in[2];
    const float* Wv = (const float*)d_in[3];
    const float* Wo = (const float*)d_in[4];
    const int* seqm = (const int*)d_in[5];
    const int* spm = (const int*)d_in[6];
    float* out = (float*)d_out;

    const size_t E = 2097152;            // 2*2048*512
    bf16* Qg = (bf16*)d_ws;              // [bh][tok][64]
    bf16* Kg = Qg + E;                   // [bh][tok][64]
    bf16* Vt = Kg + E;                   // [bh][64][2048]
    unsigned* pseq = (unsigned*)(Vt + E);
    unsigned* psp = pseq + 262144;
    float* Opart = (float*)(psp + 262144);       // 2048 slabs x 4096 fp32 = 32 MB
    float* Lpart = Opart + (size_t)2048 * 4096;  // 0.5 MB

    hipLaunchKernelGGL(qkv_mask, dim3(2816), dim3(256), 0, stream,
                       x, Wq, Wk, Wv, seqm, spm, Qg, Kg, Vt, pseq, psp);
    hipLaunchKernelGGL(attn_kernel, dim3(1024), dim3(256), 0, stream,
                       Qg, Kg, Vt, pseq, psp, Opart, Lpart);
    hipLaunchKernelGGL(gemm_out, dim3(512), dim3(256), 0, stream, Opart, Lpart, Wo, out);
}

// Round 11
// 191.521 us; speedup vs baseline: 1.0506x; 1.0457x over previous
//
#include <hip/hip_runtime.h>
#include <math.h>

typedef __bf16 bf16;
typedef __bf16 bf16x4 __attribute__((ext_vector_type(4)));
typedef __bf16 bf16x8 __attribute__((ext_vector_type(8)));
typedef float f32x4 __attribute__((ext_vector_type(4)));
typedef float f32x16 __attribute__((ext_vector_type(16)));

#define MFMA(a, b, c) __builtin_amdgcn_mfma_f32_16x16x32_bf16(a, b, c, 0, 0, 0)
#define MFMA32(a, b, c) __builtin_amdgcn_mfma_f32_32x32x16_bf16(a, b, c, 0, 0, 0)
#define LOG2E 1.44269504088896340736f

// XOR-swizzled 64x64 bf16 tile (8 KB): elem (row, chunk8) at row*64 + ((ch^(row&7))*8).
__device__ __forceinline__ void stage_tile256(bf16* __restrict__ T, const bf16* __restrict__ src,
                                              int rs, int t) {
#pragma unroll
    for (int it = 0; it < 2; ++it) {
        int u = it * 256 + t;
        int row = u >> 3, ch = u & 7;
        bf16x8 v = *(const bf16x8*)&src[(size_t)row * rs + ch * 8];
        *(bf16x8*)&T[row * 64 + ((ch ^ (row & 7)) << 3)] = v;
    }
}
__device__ __forceinline__ bf16x8 frag(const bf16* __restrict__ T, int row, int ch) {
    return *(const bf16x8*)&T[row * 64 + ((ch ^ (row & 7)) << 3)];
}

// ---------------- prep: x->bf16 [0,1024); weights [1024,1536) ----------------
__global__ __launch_bounds__(256) void prep(
    const float* __restrict__ x,
    const float* __restrict__ Wq, const float* __restrict__ Wk,
    const float* __restrict__ Wv, const float* __restrict__ Wo,
    bf16* __restrict__ xb, bf16* __restrict__ Wb,
    bf16* __restrict__ Woh, bf16* __restrict__ Wol)
{
    int bid = blockIdx.x, t = threadIdx.x;
    if (bid < 1024) {
        int i = (bid * 256 + t) * 8;
        float4 a = *(const float4*)&x[i];
        float4 c = *(const float4*)&x[i + 4];
        float v[8] = {a.x, a.y, a.z, a.w, c.x, c.y, c.z, c.w};
        bf16x8 o;
#pragma unroll
        for (int u = 0; u < 8; ++u) o[u] = (bf16)v[u];
        *(bf16x8*)&xb[i] = o;
    } else {
        int zb = bid - 1024;
        int z = zb >> 7;
        int i = ((zb & 127) * 256 + t) * 8;
        const float* src = (z == 0) ? Wq : (z == 1) ? Wk : (z == 2) ? Wv : Wo;
        float4 a = *(const float4*)&src[i];
        float4 c = *(const float4*)&src[i + 4];
        float v[8] = {a.x, a.y, a.z, a.w, c.x, c.y, c.z, c.w};
        if (z < 3) {
            bf16x8 o;
#pragma unroll
            for (int u = 0; u < 8; ++u) o[u] = (bf16)v[u];
            *(bf16x8*)&Wb[(size_t)z * 262144 + i] = o;
        } else {
            bf16x8 oh, ol;
#pragma unroll
            for (int u = 0; u < 8; ++u) {
                bf16 hi = (bf16)v[u];
                oh[u] = hi;
                ol[u] = (bf16)(v[u] - (float)hi);
            }
            *(bf16x8*)&Woh[i] = oh;
            *(bf16x8*)&Wol[i] = ol;
        }
    }
}

// ---------------- qkv GEMM (bid<768) + mask bit-pack [768,2816) overlap ----------------
__global__ __launch_bounds__(256) void qkv_mask(
    const bf16* __restrict__ A, const bf16* __restrict__ Wb,
    const int* __restrict__ seqm, const int* __restrict__ spm,
    bf16* __restrict__ Qg, bf16* __restrict__ Kg, bf16* __restrict__ Vt,
    unsigned* __restrict__ pseq, unsigned* __restrict__ psp)
{
    int bid = blockIdx.x, t = threadIdx.x;
    if (bid >= 768) {
        int wave = t >> 6, lane = t & 63;
        int row = (bid - 768) * 4 + wave;       // [0,4096)=seq, [4096,8192)=sparse
        const int* src = (row < 4096) ? (seqm + (size_t)row * 2048)
                                      : (spm + (size_t)(row - 4096) * 2048);
        unsigned* dst = (row < 4096) ? (pseq + (size_t)row * 64)
                                     : (psp + (size_t)(row - 4096) * 64);
        unsigned myw = 0;
#pragma unroll
        for (int u = 0; u < 32; ++u) {
            int v = src[u * 64 + lane];
            unsigned long long bal = __ballot(v != 0);
            if ((lane >> 1) == u)
                myw = (lane & 1) ? (unsigned)(bal >> 32) : (unsigned)bal;
        }
        dst[lane] = myw;
        return;
    }

    __shared__ bf16 AT[4096], WT0[4096], WT1[4096];
    __shared__ bf16 Lt[64 * 72];
    int m0b = bid & 63;
    int rest = bid >> 6;
    int np = rest & 3, z = rest >> 2;
    const bf16* W = Wb + (size_t)z * 262144;

    int wave = t >> 6, lane = t & 63, l = lane & 15, quad = lane >> 4;
    int m0 = m0b * 64 + wave * 16;
    int nb = np * 128;
    f32x4 acc[8] = {};
    for (int k0 = 0; k0 < 512; k0 += 64) {
        __syncthreads();
        stage_tile256(AT, A + (size_t)m0b * 64 * 512 + k0, 512, t);
        stage_tile256(WT0, W + (size_t)nb * 512 + k0, 512, t);
        stage_tile256(WT1, W + (size_t)(nb + 64) * 512 + k0, 512, t);
        __syncthreads();
        bf16x8 a0 = frag(AT, wave * 16 + l, quad);
        bf16x8 a1 = frag(AT, wave * 16 + l, 4 + quad);
#pragma unroll
        for (int nc = 0; nc < 4; ++nc) {
            bf16x8 b0 = frag(WT0, nc * 16 + l, quad);
            bf16x8 b1 = frag(WT0, nc * 16 + l, 4 + quad);
            acc[nc] = MFMA(a0, b0, acc[nc]);
            acc[nc] = MFMA(a1, b1, acc[nc]);
        }
#pragma unroll
        for (int nc = 0; nc < 4; ++nc) {
            bf16x8 b0 = frag(WT1, nc * 16 + l, quad);
            bf16x8 b1 = frag(WT1, nc * 16 + l, 4 + quad);
            acc[4 + nc] = MFMA(a0, b0, acc[4 + nc]);
            acc[4 + nc] = MFMA(a1, b1, acc[4 + nc]);
        }
    }
    if (z < 2) {
        bf16* out = (z == 0) ? Qg : Kg;
        float scale = (z == 0) ? (0.125f * LOG2E) : 1.0f;
#pragma unroll
        for (int nc = 0; nc < 8; ++nc) {
#pragma unroll
            for (int r = 0; r < 4; ++r) {
                int m = m0 + quad * 4 + r;
                int feat = nb + nc * 16 + l;
                int bb = m >> 11, tok = m & 2047, h = feat >> 6, d = feat & 63;
                out[(((size_t)(bb * 8 + h)) * 2048 + tok) * 64 + d] = (bf16)(acc[nc][r] * scale);
            }
        }
    } else {
        int b = m0b >> 5;
#pragma unroll
        for (int hh = 0; hh < 2; ++hh) {
            __syncthreads();
#pragma unroll
            for (int nc = 0; nc < 4; ++nc)
#pragma unroll
                for (int r = 0; r < 4; ++r)
                    Lt[(nc * 16 + l) * 72 + wave * 16 + quad * 4 + r] = (bf16)acc[hh * 4 + nc][r];
            __syncthreads();
            int d = t >> 2, seg = t & 3;
            int tok0 = m0b * 64;
            int h = np * 2 + hh;
            bf16x8 o0, o1;
#pragma unroll
            for (int i = 0; i < 8; ++i) { o0[i] = Lt[d * 72 + seg * 16 + i]; o1[i] = Lt[d * 72 + seg * 16 + 8 + i]; }
            size_t base = ((size_t)(b * 8 + h) * 64 + d) * 2048 + (tok0 & 2047) + seg * 16;
            *(bf16x8*)&Vt[base] = o0;
            *(bf16x8*)&Vt[base + 8] = o1;
        }
    }
}

// ---------------- flash attention on 32x32x16 MFMA ----------------
// grid 1024 = jc(2b) | it(4b) | bh(4b); 4 waves x 32 q-rows = 128 q/block sharing
// one 16 KB K/V staging. q = lane&31 everywhere; per-mt (32-j) softmax; P per-wave
// 32x36 padded. LDS 25.4 KB.
__global__ __launch_bounds__(256) void attn_kernel(
    const bf16* __restrict__ Qg, const bf16* __restrict__ Kg, const bf16* __restrict__ Vt,
    const unsigned* __restrict__ pseq, const unsigned* __restrict__ psp,
    float* __restrict__ Opart, float* __restrict__ Lpart)
{
    __shared__ bf16 KT[4096], VT[4096];
    __shared__ bf16 P[4 * 32 * 36];
    int bid = blockIdx.x;
    int bh = bid & 15;                       // XCD = bid%8 -> K/V L2-resident
    int it = (bid >> 4) & 15;
    int jc = bid >> 8;
    int i0 = it * 128;
    int b = bh >> 3, par = bh & 1;
    int t = threadIdx.x, wave = t >> 6, lane = t & 63;
    int l31 = lane & 31, h = lane >> 5;

    int qrow = i0 + wave * 32 + l31;
    // Q B-frags (B[k=d][n=q], n=lane&31, k=(lane>>5)*8+i): d = 16*kc + 8h + i
    const bf16* Qp = Qg + ((size_t)bh * 2048 + qrow) * 64 + 8 * h;
    bf16x8 qf[4];
#pragma unroll
    for (int kc = 0; kc < 4; ++kc) qf[kc] = *(const bf16x8*)&Qp[16 * kc];

    const f32x16 z16 = {};
    f32x16 o_acc[2] = {};
    float l_acc = 0.f;

    const unsigned* seqp = pseq + (size_t)b * 131072 + (size_t)qrow * 64;
    const unsigned* sppp = psp + (size_t)par * 131072 + (size_t)qrow * 64;
    const bf16* Kbase = Kg + (size_t)bh * 2048 * 64;
    const bf16* Vbase = Vt + (size_t)bh * 64 * 2048;
    bf16* Pw = P + wave * 1152;

    int jlo = jc * 512, jhi = jlo + 512;
    for (int j0 = jlo; j0 < jhi; j0 += 64) {
        uint2 mseq = *(const uint2*)&seqp[j0 >> 5];
        uint2 msp = *(const uint2*)&sppp[j0 >> 5];
        unsigned wm[2] = {mseq.x & msp.x, mseq.y & msp.y};

        __syncthreads();
        stage_tile256(KT, Kbase + (size_t)j0 * 64, 64, t);
        stage_tile256(VT, Vbase + j0, 2048, t);
        __syncthreads();

#pragma unroll
        for (int mt = 0; mt < 2; ++mt) {
            // S^T = K·Q^T : A = K[m=j][k=d] rows 32*mt.., B = Q; C col=q, row=j pattern
            f32x16 s = MFMA32(frag(KT, 32 * mt + l31, 0 + h), qf[0], z16);
            s = MFMA32(frag(KT, 32 * mt + l31, 2 + h), qf[1], s);
            s = MFMA32(frag(KT, 32 * mt + l31, 4 + h), qf[2], s);
            s = MFMA32(frag(KT, 32 * mt + l31, 6 + h), qf[3], s);

            unsigned w = wm[mt];
            float lsum_t = 0.f;
#pragma unroll
            for (int g = 0; g < 4; ++g) {
                bf16x4 pv;
#pragma unroll
                for (int r2 = 0; r2 < 4; ++r2) {
                    float e = __builtin_amdgcn_exp2f(s[4 * g + r2]);
                    float pe = ((w >> (8 * g + 4 * h + r2)) & 1u) ? e : 0.f;
                    lsum_t += pe;
                    pv[r2] = (bf16)pe;
                }
                *(bf16x4*)&Pw[l31 * 36 + 8 * g + 4 * h] = pv;
            }
            l_acc += lsum_t;

            // P A-frags (A[m=q][k=j'], same-wave LDS round trip)
            bf16x8 pa0 = *(const bf16x8*)&Pw[l31 * 36 + 8 * h];
            bf16x8 pa1 = *(const bf16x8*)&Pw[l31 * 36 + 16 + 8 * h];
#pragma unroll
            for (int nt = 0; nt < 2; ++nt) {
                o_acc[nt] = MFMA32(pa0, frag(VT, 32 * nt + l31, 2 * (2 * mt + 0) + h), o_acc[nt]);
                o_acc[nt] = MFMA32(pa1, frag(VT, 32 * nt + l31, 2 * (2 * mt + 1) + h), o_acc[nt]);
            }
        }
    }

    float lsum = l_acc + __shfl_xor(l_acc, 32);
    int slab = (bh * 32 + it * 2 + (wave >> 1)) * 4 + jc;
    int row0 = (wave & 1) * 32;
    float* Ob = Opart + (size_t)slab * 4096;
#pragma unroll
    for (int nt = 0; nt < 2; ++nt)
#pragma unroll
        for (int reg = 0; reg < 16; ++reg) {
            int row = row0 + (reg & 3) + 8 * (reg >> 2) + 4 * h;
            Ob[(size_t)row * 64 + 32 * nt + l31] = o_acc[nt][reg];
        }
    if (h == 0)
        Lpart[slab * 64 + row0 + l31] = lsum;
}

// ---------------- combine partials -> normalized split-bf16 O ----------------
__global__ __launch_bounds__(256) void attn_combine(
    const float* __restrict__ Opart, const float* __restrict__ Lpart,
    bf16* __restrict__ Oh, bf16* __restrict__ Ol)
{
    int blk = blockIdx.x;
    int bh = blk >> 5, it = blk & 31;
    int t = threadIdx.x;
    int row = t >> 2, dseg = (t & 3) << 4;

    float acc[16] = {};
    float lsum = 0.f;
#pragma unroll
    for (int jc = 0; jc < 4; ++jc) {
        const float* Op = Opart + ((size_t)(blk * 4 + jc)) * 4096 + (size_t)row * 64 + dseg;
#pragma unroll
        for (int u = 0; u < 4; ++u) {
            float4 v = *(const float4*)&Op[u * 4];
            acc[u * 4 + 0] += v.x; acc[u * 4 + 1] += v.y;
            acc[u * 4 + 2] += v.z; acc[u * 4 + 3] += v.w;
        }
        lsum += Lpart[(blk * 4 + jc) * 64 + row];
    }
    float inv = 1.0f / lsum;
    int b = bh >> 3, h = bh & 7, tok = it * 64 + row;
    size_t base = ((size_t)b * 2048 + tok) * 512 + h * 64 + dseg;
    bf16x8 oh0, oh1, ol0, ol1;
#pragma unroll
    for (int u = 0; u < 8; ++u) {
        float v0 = acc[u] * inv, v1 = acc[8 + u] * inv;
        bf16 h0 = (bf16)v0, h1 = (bf16)v1;
        oh0[u] = h0; ol0[u] = (bf16)(v0 - (float)h0);
        oh1[u] = h1; ol1[u] = (bf16)(v1 - (float)h1);
    }
    *(bf16x8*)&Oh[base] = oh0;
    *(bf16x8*)&Oh[base + 8] = oh1;
    *(bf16x8*)&Ol[base] = ol0;
    *(bf16x8*)&Ol[base + 8] = ol1;
}

// ---------------- output projection, LDS-staged split-bf16 ----------------
__global__ __launch_bounds__(256) void gemm_out(
    const bf16* __restrict__ Ah, const bf16* __restrict__ Al,
    const bf16* __restrict__ Wh, const bf16* __restrict__ Wl,
    float* __restrict__ C)
{
    __shared__ bf16 AhT[4096], AlT[4096], WhT[4096], WlT[4096];
    int bid = blockIdx.x;
    int m0b = bid & 63, n0 = bid >> 6;
    int t = threadIdx.x, wave = t >> 6, lane = t & 63, l = lane & 15, quad = lane >> 4;
    int m0 = m0b * 64 + wave * 16;
    int nb = n0 * 64;
    f32x4 acc[4] = {};
    for (int k0 = 0; k0 < 512; k0 += 64) {
        __syncthreads();
        stage_tile256(AhT, Ah + (size_t)m0b * 64 * 512 + k0, 512, t);
        stage_tile256(AlT, Al + (size_t)m0b * 64 * 512 + k0, 512, t);
        stage_tile256(WhT, Wh + (size_t)nb * 512 + k0, 512, t);
        stage_tile256(WlT, Wl + (size_t)nb * 512 + k0, 512, t);
        __syncthreads();
        bf16x8 ah0 = frag(AhT, wave * 16 + l, quad);
        bf16x8 ah1 = frag(AhT, wave * 16 + l, 4 + quad);
        bf16x8 al0 = frag(AlT, wave * 16 + l, quad);
        bf16x8 al1 = frag(AlT, wave * 16 + l, 4 + quad);
#pragma unroll
        for (int nc = 0; nc < 4; ++nc) {
            bf16x8 bh0 = frag(WhT, nc * 16 + l, quad);
            bf16x8 bh1 = frag(WhT, nc * 16 + l, 4 + quad);
            bf16x8 bl0 = frag(WlT, nc * 16 + l, quad);
            bf16x8 bl1 = frag(WlT, nc * 16 + l, 4 + quad);
            acc[nc] = MFMA(ah0, bh0, acc[nc]);
            acc[nc] = MFMA(ah1, bh1, acc[nc]);
            acc[nc] = MFMA(ah0, bl0, acc[nc]);
            acc[nc] = MFMA(ah1, bl1, acc[nc]);
            acc[nc] = MFMA(al0, bh0, acc[nc]);
            acc[nc] = MFMA(al1, bh1, acc[nc]);
        }
    }
#pragma unroll
    for (int nc = 0; nc < 4; ++nc)
#pragma unroll
        for (int r = 0; r < 4; ++r)
            C[(size_t)(m0 + quad * 4 + r) * 512 + nb + nc * 16 + l] = acc[nc][r];
}

extern "C" void kernel_launch(void* const* d_in, const int* in_sizes, int n_in,
                              void* d_out, int out_size, void* d_ws, size_t ws_size,
                              hipStream_t stream) {
    const float* x = (const float*)d_in[0];
    const float* Wq = (const float*)d_in[1];
    const float* Wk = (const float*)d_in[2];
    const float* Wv = (const float*)d_in[3];
    const float* Wo = (const float*)d_in[4];
    const int* seqm = (const int*)d_in[5];
    const int* spm = (const int*)d_in[6];
    float* out = (float*)d_out;

    const size_t E = 2097152;            // 2*2048*512
    bf16* xb = (bf16*)d_ws;
    bf16* Wb = xb + E;
    bf16* Woh = Wb + 786432;
    bf16* Wol = Woh + 262144;
    bf16* Qg = Wol + 262144;
    bf16* Kg = Qg + E;
    bf16* Vt = Kg + E;                   // [bh][64][2048]
    bf16* Ohb = Vt + E;
    bf16* Olb = Ohb + E;
    unsigned* pseq = (unsigned*)(Olb + E);
    unsigned* psp = pseq + 262144;
    float* Opart = (float*)(psp + 262144);       // 2048 x 4096 fp32 = 32 MB
    float* Lpart = Opart + (size_t)2048 * 4096;  // 0.5 MB

    hipLaunchKernelGGL(prep, dim3(1536), dim3(256), 0, stream,
                       x, Wq, Wk, Wv, Wo, xb, Wb, Woh, Wol);
    hipLaunchKernelGGL(qkv_mask, dim3(2816), dim3(256), 0, stream,
                       xb, Wb, seqm, spm, Qg, Kg, Vt, pseq, psp);
    hipLaunchKernelGGL(attn_kernel, dim3(1024), dim3(256), 0, stream,
                       Qg, Kg, Vt, pseq, psp, Opart, Lpart);
    hipLaunchKernelGGL(attn_combine, dim3(512), dim3(256), 0, stream, Opart, Lpart, Ohb, Olb);
    hipLaunchKernelGGL(gemm_out, dim3(512), dim3(256), 0, stream, Ohb, Olb, Woh, Wol, out);
}